// Round 1
// baseline (2388.273 us; speedup 1.0000x reference)
//
#include <hip/hip_runtime.h>
#include <math.h>

// Problem dims
#define Bb 256
#define Nn 196
#define Dd 512
#define Hh 102
#define Kk 64
#define Mm 40

// ws layout: logits [B][2][N][K] f32 = 25,690,112 B ; aggP [2][B][K][D] f32 = 67,108,864 B
// total required ws = 92,798,976 B
#define LOGITS_BYTES 25690112

__device__ __forceinline__ float dot4(const float4 a, const float4 b) {
  return a.x*b.x + a.y*b.y + a.z*b.z + a.w*b.w;
}

__device__ __forceinline__ float wave_reduce_sum(float v) {
#pragma unroll
  for (int o = 1; o < 64; o <<= 1) v += __shfl_xor(v, o, 64);
  return v;
}

// ---------------------------------------------------------------------------
// K1: per 112-token tile of one (b, path): LN -> gelu(x@w1+b1) -> @w2+b2
// writes logits [b][p][n][k] (k contiguous)
// ---------------------------------------------------------------------------
__global__ __launch_bounds__(256) void k1_logits(
    const float* __restrict__ x_s, const float* __restrict__ x_d,
    const float* __restrict__ g_s, const float* __restrict__ bb_s,
    const float* __restrict__ w1_s, const float* __restrict__ b1_s,
    const float* __restrict__ w2_s, const float* __restrict__ b2_s,
    const float* __restrict__ g_d, const float* __restrict__ bb_d,
    const float* __restrict__ w1_d, const float* __restrict__ b1_d,
    const float* __restrict__ w2_d, const float* __restrict__ b2_d,
    float* __restrict__ logits)
{
  // phase1: gs(512) bs(512) st(224) xs(112x36) w1t(128x36)  = 39552 B
  // phase2: hs(112x104) w2t(32x108)                          = 60416 B (union size)
  __shared__ __align__(16) float smem[15104];
  float* gs  = smem;
  float* bs  = smem + 512;
  float* st  = smem + 1024;   // [112][2] mu, rstd
  float* xs  = smem + 1248;   // [112][36]
  float* w1t = smem + 5280;   // [128][36]  (j-major, c-local minor)
  float* hs  = smem;          // [112][104]
  float* w2t = smem + 11648;  // [32][108]  (k-local major, j minor)

  const int tid = threadIdx.x;
  const int ntile = blockIdx.x, p = blockIdx.y, b = blockIdx.z;
  const int nbase = ntile * 112;
  const float* x  = p ? x_d  : x_s;
  const float* gp = p ? g_d  : g_s;
  const float* bp = p ? bb_d : bb_s;
  const float* w1 = p ? w1_d : w1_s;
  const float* b1 = p ? b1_d : b1_s;
  const float* w2 = p ? w2_d : w2_s;
  const float* b2 = p ? b2_d : b2_s;

  gs[tid] = gp[tid]; gs[tid + 256] = gp[tid + 256];
  bs[tid] = bp[tid]; bs[tid + 256] = bp[tid + 256];

  // LN stats: wave per token
  const int wv = tid >> 6, lane = tid & 63;
  for (int i = 0; i < 28; ++i) {
    const int t = wv + 4 * i;
    const int n = nbase + t;
    float s = 0.f, ss = 0.f;
    if (n < Nn) {
      const float* xr = x + ((size_t)(b * Nn + n)) * Dd;
      float4 a = *(const float4*)(xr + lane * 4);
      float4 c = *(const float4*)(xr + 256 + lane * 4);
      s  = a.x + a.y + a.z + a.w + c.x + c.y + c.z + c.w;
      ss = dot4(a, a) + dot4(c, c);
    }
    s = wave_reduce_sum(s); ss = wave_reduce_sum(ss);
    if (lane == 0) {
      float mu  = s * (1.f / 512.f);
      float var = fmaxf(ss * (1.f / 512.f) - mu * mu, 0.f);
      st[2 * t]     = mu;
      st[2 * t + 1] = (n < Nn) ? rsqrtf(var + 1e-5f) : 0.f;
    }
  }
  __syncthreads();

  // h-GEMM: thread (ti, ji) owns t = ti+16l (l<7), j = ji*8+m (m<8), 128 j padded
  const int ti = tid & 15, ji = tid >> 4;
  float acc[7][8];
#pragma unroll
  for (int l = 0; l < 7; ++l)
#pragma unroll
    for (int m = 0; m < 8; ++m) acc[l][m] = 0.f;

  for (int ch = 0; ch < 16; ++ch) {
    const int c0 = ch * 32;
    __syncthreads();
    // stage w1 chunk transposed: w1t[j][cl]
    for (int idx = tid; idx < 3264; idx += 256) {
      int cl = idx / 102;
      int j  = idx - cl * 102;
      w1t[j * 36 + cl] = w1[(size_t)(c0 + cl) * Hh + j];
    }
    // zero pad rows j=102..127
    for (int idx = tid; idx < 936; idx += 256) {
      int j  = 102 + idx / 36;
      int cl = idx - (idx / 36) * 36;
      w1t[j * 36 + cl] = 0.f;
    }
    // stage x chunk with LN applied
    for (int idx = tid; idx < 896; idx += 256) {
      int t = idx >> 3, cf = idx & 7;
      int n = nbase + t;
      float mu = st[2 * t], rs = st[2 * t + 1];
      float4 v = {0.f, 0.f, 0.f, 0.f};
      if (n < Nn) v = *(const float4*)(x + ((size_t)(b * Nn + n)) * Dd + c0 + cf * 4);
      int c = c0 + cf * 4;
      float4 o;
      o.x = (v.x - mu) * rs * gs[c]     + bs[c];
      o.y = (v.y - mu) * rs * gs[c + 1] + bs[c + 1];
      o.z = (v.z - mu) * rs * gs[c + 2] + bs[c + 2];
      o.w = (v.w - mu) * rs * gs[c + 3] + bs[c + 3];
      *(float4*)(xs + t * 36 + cf * 4) = o;
    }
    __syncthreads();
#pragma unroll
    for (int cq = 0; cq < 8; ++cq) {
      float4 xq[7], wq[8];
#pragma unroll
      for (int l = 0; l < 7; ++l) xq[l] = *(const float4*)(xs + (ti + 16 * l) * 36 + cq * 4);
#pragma unroll
      for (int m = 0; m < 8; ++m) wq[m] = *(const float4*)(w1t + (ji * 8 + m) * 36 + cq * 4);
#pragma unroll
      for (int l = 0; l < 7; ++l)
#pragma unroll
        for (int m = 0; m < 8; ++m)
          acc[l][m] += dot4(xq[l], wq[m]);
    }
  }

  // bias + exact gelu, write h to LDS (union flip)
  float b1r[8];
#pragma unroll
  for (int m = 0; m < 8; ++m) {
    int j = ji * 8 + m;
    b1r[m] = (j < Hh) ? b1[j] : 0.f;
  }
  __syncthreads();
#pragma unroll
  for (int l = 0; l < 7; ++l) {
    int t = ti + 16 * l;
#pragma unroll
    for (int m = 0; m < 8; ++m) {
      int j = ji * 8 + m;
      if (j < 104) {
        float z = acc[l][m] + b1r[m];
        hs[t * 104 + j] = 0.5f * z * (1.f + erff(z * 0.70710678118f));
      }
    }
  }

  // logits GEMM in two k-halves of 32
  const int ki = tid & 7, ti2 = tid >> 3;
  for (int half = 0; half < 2; ++half) {
    __syncthreads();
    for (int idx = tid; idx < 3264; idx += 256) {
      int j = idx >> 5, ko = idx & 31;
      w2t[ko * 108 + j] = w2[(size_t)j * Kk + half * 32 + ko];
    }
    for (int idx = tid; idx < 192; idx += 256) {
      int ko = idx / 6, jp = 102 + (idx - (idx / 6) * 6);
      w2t[ko * 108 + jp] = 0.f;
    }
    __syncthreads();
    float acc2[4][4];
#pragma unroll
    for (int l = 0; l < 4; ++l)
#pragma unroll
      for (int kk = 0; kk < 4; ++kk) acc2[l][kk] = 0.f;
    int tcl[4];
#pragma unroll
    for (int l = 0; l < 4; ++l) tcl[l] = min(ti2 + 32 * l, 111);
#pragma unroll
    for (int jq = 0; jq < 26; ++jq) {
      float4 hq[4], wq2[4];
#pragma unroll
      for (int l = 0; l < 4; ++l)   hq[l]   = *(const float4*)(hs + tcl[l] * 104 + jq * 4);
#pragma unroll
      for (int kk = 0; kk < 4; ++kk) wq2[kk] = *(const float4*)(w2t + (ki * 4 + kk) * 108 + jq * 4);
#pragma unroll
      for (int l = 0; l < 4; ++l)
#pragma unroll
        for (int kk = 0; kk < 4; ++kk)
          acc2[l][kk] += dot4(hq[l], wq2[kk]);
    }
    const float4 b2v = *(const float4*)(b2 + half * 32 + ki * 4);
#pragma unroll
    for (int l = 0; l < 4; ++l) {
      int t = ti2 + 32 * l, n = nbase + t;
      if (t < 112 && n < Nn) {
        float4 o = {acc2[l][0] + b2v.x, acc2[l][1] + b2v.y,
                    acc2[l][2] + b2v.z, acc2[l][3] + b2v.w};
        *(float4*)(logits + ((size_t)(b * 2 + p) * Nn + n) * Kk + half * 32 + ki * 4) = o;
      }
    }
  }
}

// ---------------------------------------------------------------------------
// K2: per (p, b): softmax over n (scale pre-applied), then agg = w @ x
// writes aggP [p][b][k][c]
// ---------------------------------------------------------------------------
__global__ __launch_bounds__(512) void k2_softmax_agg(
    const float* __restrict__ x_s, const float* __restrict__ x_d,
    const float* __restrict__ logits, const float* __restrict__ scale,
    float* __restrict__ aggP)
{
  __shared__ __align__(16) float wt[196 * 68];   // [n][k] padded
  __shared__ __align__(16) float xt[4 * 512];
  __shared__ float red[8 * 64];
  __shared__ float mxk[64];
  __shared__ float rsk[64];
  const int tid = threadIdx.x;
  const int p = blockIdx.x, b = blockIdx.y;
  const float* x = p ? x_d : x_s;
  const float sc = scale[0];
  const float* lg = logits + (size_t)(b * 2 + p) * Nn * Kk;
  for (int idx = tid; idx < Nn * Kk; idx += 512) {
    int n = idx >> 6, k = idx & 63;
    wt[n * 68 + k] = lg[idx] * sc;
  }
  __syncthreads();
  const int k = tid & 63, g = tid >> 6;
  float mloc = -1e30f;
  for (int n = g; n < Nn; n += 8) mloc = fmaxf(mloc, wt[n * 68 + k]);
  red[g * 64 + k] = mloc;
  __syncthreads();
  if (g == 0) {
    float mm = red[k];
#pragma unroll
    for (int gg = 1; gg < 8; ++gg) mm = fmaxf(mm, red[gg * 64 + k]);
    mxk[k] = mm;
  }
  __syncthreads();
  const float mk = mxk[k];
  float sloc = 0.f;
  for (int n = g; n < Nn; n += 8) {
    float e = expf(wt[n * 68 + k] - mk);
    wt[n * 68 + k] = e;
    sloc += e;
  }
  red[g * 64 + k] = sloc;
  __syncthreads();
  if (g == 0) {
    float sm = red[k];
#pragma unroll
    for (int gg = 1; gg < 8; ++gg) sm += red[gg * 64 + k];
    rsk[k] = 1.f / sm;
  }
  __syncthreads();
  const float rk = rsk[k];
  for (int n = g; n < Nn; n += 8) wt[n * 68 + k] *= rk;

  // agg: wave kg owns k = kg*8+kk; lane cg owns c = cg*4 + 256q
  const int kg = tid >> 6, cg = tid & 63;
  float acc[8][8];
#pragma unroll
  for (int kk = 0; kk < 8; ++kk)
#pragma unroll
    for (int e = 0; e < 8; ++e) acc[kk][e] = 0.f;

  for (int nt = 0; nt < 49; ++nt) {
    const int n0 = nt * 4;
    __syncthreads();   // also orders softmax writes before first agg reads
    {
      int row = tid >> 7, cf = tid & 127;
      float4 v = *(const float4*)(x + ((size_t)(b * Nn + n0 + row)) * Dd + cf * 4);
      *(float4*)(xt + row * 512 + cf * 4) = v;
    }
    __syncthreads();
#pragma unroll
    for (int i = 0; i < 4; ++i) {
      const int n = n0 + i;
      float4 wa = *(const float4*)(wt + n * 68 + kg * 8);
      float4 wb = *(const float4*)(wt + n * 68 + kg * 8 + 4);
      float4 xa = *(const float4*)(xt + i * 512 + cg * 4);
      float4 xb = *(const float4*)(xt + i * 512 + 256 + cg * 4);
      float wv8[8] = {wa.x, wa.y, wa.z, wa.w, wb.x, wb.y, wb.z, wb.w};
      float xv8[8] = {xa.x, xa.y, xa.z, xa.w, xb.x, xb.y, xb.z, xb.w};
#pragma unroll
      for (int kk = 0; kk < 8; ++kk)
#pragma unroll
        for (int e = 0; e < 8; ++e)
          acc[kk][e] += wv8[kk] * xv8[e];
    }
  }
#pragma unroll
  for (int kk = 0; kk < 8; ++kk) {
    size_t base = ((size_t)((p * Bb + b) * Kk + kg * 8 + kk)) * Dd;
    float4 o0 = {acc[kk][0], acc[kk][1], acc[kk][2], acc[kk][3]};
    float4 o1 = {acc[kk][4], acc[kk][5], acc[kk][6], acc[kk][7]};
    *(float4*)(aggP + base + cg * 4) = o0;
    *(float4*)(aggP + base + 256 + cg * 4) = o1;
  }
}

// ---------------------------------------------------------------------------
// K4: per b: v = l2norm(agg_s+agg_d), t = l2norm(words), sim -> leaky -> pools
// ---------------------------------------------------------------------------
__global__ __launch_bounds__(256) void k4_final(
    const float* __restrict__ words, const float* __restrict__ aggP,
    float* __restrict__ outp)
{
  __shared__ __align__(16) float vsm[16 * 512];
  __shared__ float rnv[16];
  __shared__ float colp[4 * 64];
  __shared__ float rowm[40];
  const int tid = threadIdx.x, b = blockIdx.x;
  const int w = tid >> 6, lane = tid & 63;
  const float* a0 = aggP + (size_t)b * Kk * Dd;
  const float* a1 = aggP + ((size_t)(Bb + b)) * Kk * Dd;
  if (tid < 40) rowm[tid] = -1e30f;
  float cm = -1e30f;

  for (int kc = 0; kc < 4; ++kc) {
    __syncthreads();
    for (int idx = tid; idx < 2048; idx += 256) {
      int r = idx >> 7, cf = idx & 127;
      size_t off = ((size_t)(kc * 16 + r)) * Dd + cf * 4;
      float4 u = *(const float4*)(a0 + off);
      float4 v = *(const float4*)(a1 + off);
      float4 s4 = {u.x + v.x, u.y + v.y, u.z + v.z, u.w + v.w};
      *(float4*)(vsm + r * 512 + cf * 4) = s4;
    }
    __syncthreads();
#pragma unroll
    for (int i = 0; i < 4; ++i) {
      int r = w * 4 + i;
      float4 aq = *(const float4*)(vsm + r * 512 + lane * 4);
      float4 bq = *(const float4*)(vsm + r * 512 + 256 + lane * 4);
      float ss = wave_reduce_sum(dot4(aq, aq) + dot4(bq, bq));
      if (lane == 0) rnv[r] = 1.f / fmaxf(sqrtf(ss), 1e-8f);
    }
    __syncthreads();
    for (int i = 0; i < 10; ++i) {
      const int m = w + 4 * i;
      const float* tr = words + ((size_t)(b * Mm + m)) * Dd;
      float4 ta = *(const float4*)(tr + lane * 4);
      float4 tb = *(const float4*)(tr + 256 + lane * 4);
      float ss = wave_reduce_sum(dot4(ta, ta) + dot4(tb, tb));
      float rnt = 1.f / fmaxf(sqrtf(ss), 1e-8f);
      float rmax_loc = -1e30f;
#pragma unroll
      for (int kk = 0; kk < 16; ++kk) {
        float4 va = *(const float4*)(vsm + kk * 512 + lane * 4);
        float4 vb = *(const float4*)(vsm + kk * 512 + 256 + lane * 4);
        float d = wave_reduce_sum(dot4(ta, va) + dot4(tb, vb));
        float s = d * rnt * rnv[kk];
        s = (s >= 0.f) ? s : 0.1f * s;
        rmax_loc = fmaxf(rmax_loc, s);
        if (lane == (kc * 16 + kk)) cm = fmaxf(cm, s);
      }
      if (lane == 0) rowm[m] = fmaxf(rowm[m], rmax_loc);
    }
  }
  colp[w * 64 + lane] = cm;
  __syncthreads();
  if (w == 0) {
    float c2 = fmaxf(fmaxf(colp[lane], colp[64 + lane]),
                     fmaxf(colp[128 + lane], colp[192 + lane]));
    float csum = wave_reduce_sum(c2);
    float rv = (lane < 40) ? rowm[lane] : 0.f;
    float rsum = wave_reduce_sum(rv);
    if (lane == 0) outp[b] = rsum * (1.f / 40.f) + csum * (1.f / 64.f);
  }
}

extern "C" void kernel_launch(void* const* d_in, const int* in_sizes, int n_in,
                              void* d_out, int out_size, void* d_ws, size_t ws_size,
                              hipStream_t stream)
{
  const float* x_s   = (const float*)d_in[0];
  const float* x_d   = (const float*)d_in[1];
  const float* words = (const float*)d_in[2];
  const float* g_s   = (const float*)d_in[3];
  const float* b_s   = (const float*)d_in[4];
  const float* w1_s  = (const float*)d_in[5];
  const float* b1_s  = (const float*)d_in[6];
  const float* w2_s  = (const float*)d_in[7];
  const float* b2_s  = (const float*)d_in[8];
  const float* g_d   = (const float*)d_in[9];
  const float* b_d   = (const float*)d_in[10];
  const float* w1_d  = (const float*)d_in[11];
  const float* b1_d  = (const float*)d_in[12];
  const float* w2_d  = (const float*)d_in[13];
  const float* b2_d  = (const float*)d_in[14];
  const float* scale = (const float*)d_in[15];
  (void)in_sizes; (void)n_in; (void)out_size; (void)ws_size;

  float* logits = (float*)d_ws;
  float* aggP   = (float*)((char*)d_ws + LOGITS_BYTES);

  hipLaunchKernelGGL(k1_logits, dim3(2, 2, 256), dim3(256), 0, stream,
                     x_s, x_d, g_s, b_s, w1_s, b1_s, w2_s, b2_s,
                     g_d, b_d, w1_d, b1_d, w2_d, b2_d, logits);
  hipLaunchKernelGGL(k2_softmax_agg, dim3(2, 256), dim3(512), 0, stream,
                     x_s, x_d, logits, scale, aggP);
  hipLaunchKernelGGL(k4_final, dim3(256), dim3(256), 0, stream,
                     words, aggP, (float*)d_out);
}